// Round 10
// baseline (172.177 us; speedup 1.0000x reference)
//
#include <hip/hip_runtime.h>

#define B_ 16
#define DIN 256
#define K_ 24
#define D_ 128
#define KD_ 3072
#define CH 64        /* rows per block chunk */
#define NS 16        /* chunks per batch */
#define EPS_ 1e-7f

// sc1 (agent-scope) accessors: single L2-bypassing load/store, no cache ops.
__device__ __forceinline__ float cl(const float* p) {
    return __hip_atomic_load(p, __ATOMIC_RELAXED, __HIP_MEMORY_SCOPE_AGENT);
}
__device__ __forceinline__ void cs(float* p, float v) {
    __hip_atomic_store(p, v, __ATOMIC_RELAXED, __HIP_MEMORY_SCOPE_AGENT);
}
__device__ __forceinline__ unsigned clu(const unsigned* p) {
    return __hip_atomic_load(p, __ATOMIC_RELAXED, __HIP_MEMORY_SCOPE_AGENT);
}
__device__ __forceinline__ unsigned fadd(unsigned* p) {
    return __hip_atomic_fetch_add(p, 1u, __ATOMIC_RELAXED, __HIP_MEMORY_SCOPE_AGENT);
}

// ---- sv tail, executed by the last 4 arriving blocks of a batch (rank 0..3,
// 6 capsules each). Ordering proof: every producer drained vmcnt(0) (the
// __syncthreads before its fadd) BEFORE adding, so cnt==16 => all partials
// MALL-visible; readers use sc1 loads. Values deterministic (fixed reduce order).
// MODE 0: t from tupart (uniform, /24), write w2. MODE 1: t from tpart k-slice,
// write w2. MODE 2: t from tpart, write out only.
template<int MODE>
__device__ __forceinline__ void sv_tail(int b, int rank, int t,
                                        const float* __restrict__ W,
                                        const float* __restrict__ tupart,
                                        const float* __restrict__ tpart,
                                        float* __restrict__ w2o,
                                        float* __restrict__ outv,
                                        float* t_lds, float* s_lds, float* v_lds) {
    const int kbase = rank * 6;
    // t-reduce
    if (MODE == 0) {
        if (t < DIN) {
            float a = 0.f;
            #pragma unroll
            for (int s2 = 0; s2 < NS; ++s2)
                a += cl(tupart + (size_t)(b * NS + s2) * DIN + t);
            t_lds[t] = a * (1.f / 24.f);
        }
    } else {
        #pragma unroll
        for (int r = 0; r < 3; ++r) {
            const int idx = r * 512 + t, kk = idx >> 8, i = idx & 255;
            float a = 0.f;
            #pragma unroll
            for (int s2 = 0; s2 < NS; ++s2)
                a += cl(tpart + (size_t)((b * NS + s2) * K_ + kbase + kk) * DIN + i);
            t_lds[kk * DIN + i] = a;
        }
    }
    __syncthreads();
    // s-pass: s[k,d] = sum_i t[k,i]*W[i,k*128+d]; 4 k's then 2 k's
    {
        const int d = t & 127;
        const int kA = t >> 7;  // 0..3
        const float* tpA = (MODE == 0) ? t_lds : (t_lds + kA * DIN);
        const float* WA = W + (size_t)(kbase + kA) * D_ + d;
        float sA = 0.f;
        #pragma unroll 8
        for (int i = 0; i < DIN; ++i) sA += tpA[i] * WA[(size_t)i * KD_];
        s_lds[kA * D_ + d] = sA;
        if (t < 256) {
            const int kB = 4 + (t >> 7);  // 4..5
            const float* tpB = (MODE == 0) ? t_lds : (t_lds + kB * DIN);
            const float* WB = W + (size_t)(kbase + kB) * D_ + d;
            float sB = 0.f;
            #pragma unroll 8
            for (int i = 0; i < DIN; ++i) sB += tpB[i] * WB[(size_t)i * KD_];
            s_lds[kB * D_ + d] = sB;
        }
    }
    __syncthreads();
    // squash: wave w handles capsule kbase+w
    {
        const int w = t >> 6, l = t & 63;
        if (w < 6) {
            const float s0 = s_lds[w * D_ + l], s1 = s_lds[w * D_ + l + 64];
            float sq = s0 * s0 + s1 * s1;
            #pragma unroll
            for (int m = 1; m < 64; m <<= 1) sq += __shfl_xor(sq, m);
            const float inv = rsqrtf(sq + EPS_);
            if (MODE == 2) {
                float* op = outv + (size_t)(b * K_ + kbase + w) * D_;
                op[l] = s0 * inv; op[l + 64] = s1 * inv;
            } else {
                v_lds[w * D_ + l] = s0 * inv;
                v_lds[w * D_ + l + 64] = s1 * inv;
            }
        }
    }
    if (MODE == 2) return;
    __syncthreads();
    // w2-pass: w2[k,i] = sum_d v[k,d]*W[i,k*128+d]; 4 lanes per (k,i) over d
    {
        const int dq = t & 3;
        #pragma unroll
        for (int r = 0; r < 12; ++r) {
            const int item = r * 128 + (t >> 2);  // 0..1535
            const int kk = item >> 8, i = item & 255;
            const float4* Wp = (const float4*)(W + (size_t)i * KD_ +
                                               (size_t)(kbase + kk) * D_ + dq * 32);
            const float4* vp = (const float4*)(v_lds + kk * D_ + dq * 32);
            float a = 0.f;
            #pragma unroll
            for (int m = 0; m < 8; ++m) {
                const float4 wv = Wp[m], vv = vp[m];
                a += wv.x * vv.x + wv.y * vv.y + wv.z * vv.z + wv.w * vv.w;
            }
            a += __shfl_xor(a, 1);
            a += __shfl_xor(a, 2);
            if (dq == 0) cs(w2o + (size_t)(b * K_ + kbase + kk) * DIN + i, a);
        }
    }
}

// helper: arrive at per-batch counter; returns rank (0..3) for tail blocks,
// -1 otherwise. Ranks 0..2 spin only for their <=3 sibling stragglers.
__device__ __forceinline__ int arrive(unsigned* cnt_b, int t, int* rank_sh) {
    __syncthreads();  // compiler emits vmcnt(0) per wave: sc1 stores MALL-acked
    if (t == 0) *rank_sh = (int)fadd(cnt_b) - 12;
    __syncthreads();
    const int rank = *rank_sh;
    if (rank < 0) return -1;
    if (rank < 3) {
        if (t == 0)
            while (clu(cnt_b) < 16u) __builtin_amdgcn_s_sleep(1);
        __syncthreads();
    }
    asm volatile("" ::: "memory");
    return rank;
}

// ---- K0: per-chunk colsum -> tupart; last 4 blocks/batch: sv0 -> w2a
__global__ __launch_bounds__(512) void k0(const float* __restrict__ u,
                                          const float* __restrict__ W,
                                          float* __restrict__ tupart,
                                          float* __restrict__ w2a,
                                          unsigned* __restrict__ cnt) {
    const int beta = blockIdx.x, b = beta >> 4, t = threadIdx.x;
    __shared__ float red[8 * DIN];       // 8 KB
    __shared__ float t_lds[DIN];
    __shared__ float s_lds[6 * D_];
    __shared__ float v_lds[6 * D_];
    __shared__ int rank_sh;
    {
        const float4* ug = (const float4*)(u + (size_t)beta * CH * DIN);
        const int g = t & 63, h = t >> 6;
        float ax = 0.f, ay = 0.f, az = 0.f, aw = 0.f;
        #pragma unroll
        for (int r = 0; r < 8; ++r) {
            const float4 v = ug[(size_t)(h * 8 + r) * 64 + g];
            ax += v.x; ay += v.y; az += v.z; aw += v.w;
        }
        float* dst = red + h * DIN + g * 4;
        dst[0] = ax; dst[1] = ay; dst[2] = az; dst[3] = aw;
    }
    __syncthreads();
    if (t < DIN) {
        float a = 0.f;
        #pragma unroll
        for (int h2 = 0; h2 < 8; ++h2) a += red[h2 * DIN + t];
        cs(tupart + (size_t)beta * DIN + t, a);
    }
    const int rank = arrive(cnt + b * 16, t, &rank_sh);
    if (rank < 0) return;
    sv_tail<0>(b, rank, t, W, tupart, nullptr, w2a, nullptr, t_lds, s_lds, v_lds);
}

// ---- K1/K2: fused (logits + softmax + t-partials); last 4 blocks/batch: sv
template<int LAST>
__global__ __launch_bounds__(512) void kfused(const float* __restrict__ u,
                                              const float* __restrict__ W,
                                              const float* __restrict__ w2in,
                                              float* __restrict__ tpart,
                                              float* __restrict__ w2out,
                                              float* __restrict__ outv,
                                              unsigned* __restrict__ cnt) {
    const int beta = blockIdx.x, b = beta >> 4, t = threadIdx.x;
    __shared__ float u_lds[CH * 257];                 // 65,792 B
    __shared__ __align__(16) float w2_lds[K_ * DIN];  // 24,576 B
    __shared__ __align__(16) float c_lds[CH * 28];    //  7,168 B
    __shared__ float t_lds[6 * DIN];                  //  6,144 B
    __shared__ float s_lds[6 * D_];
    __shared__ float v_lds[6 * D_];
    __shared__ int rank_sh;
    // stage u chunk + w2in[b]
    {
        const float4* ug = (const float4*)(u + (size_t)beta * CH * DIN);
        #pragma unroll
        for (int r = 0; r < 8; ++r) {
            const int idx = t + r * 512, n = idx >> 6, q = idx & 63;
            const float4 v = ug[(size_t)n * 64 + q];
            float* dst = u_lds + n * 257 + q * 4;
            dst[0] = v.x; dst[1] = v.y; dst[2] = v.z; dst[3] = v.w;
        }
        const float* w2g = w2in + (size_t)b * K_ * DIN;
        #pragma unroll
        for (int r = 0; r < 12; ++r)
            w2_lds[r * 512 + t] = cl(w2g + r * 512 + t);
    }
    __syncthreads();
    // logits + softmax (8-lane groups per n; softmax redundant per lane,
    // lane p==0 writes 24 c's with STATIC indices only)
    {
        const int n = t >> 3, p = t & 7;
        float acc[K_];
        #pragma unroll
        for (int k = 0; k < K_; ++k) acc[k] = 0.f;
        #pragma unroll
        for (int g = 0; g < 8; ++g) {
            const int i0 = p * 4 + g * 32;
            const float ua0 = u_lds[n * 257 + i0],     ua1 = u_lds[n * 257 + i0 + 1];
            const float ua2 = u_lds[n * 257 + i0 + 2], ua3 = u_lds[n * 257 + i0 + 3];
            #pragma unroll
            for (int k = 0; k < K_; ++k) {
                const float4 wq = *(const float4*)(w2_lds + k * DIN + i0);
                acc[k] += ua0 * wq.x + ua1 * wq.y + ua2 * wq.z + ua3 * wq.w;
            }
        }
        #pragma unroll
        for (int m = 1; m < 8; m <<= 1)
            #pragma unroll
            for (int k = 0; k < K_; ++k) acc[k] += __shfl_xor(acc[k], m);
        float mx = acc[0];
        #pragma unroll
        for (int k = 1; k < K_; ++k) mx = fmaxf(mx, acc[k]);
        float sm = 0.f;
        #pragma unroll
        for (int k = 0; k < K_; ++k) { acc[k] = __expf(acc[k] - mx); sm += acc[k]; }
        const float cinv = 1.f / sm;
        if (p == 0) {
            #pragma unroll
            for (int k = 0; k < K_; ++k) c_lds[n * 28 + k] = acc[k] * cinv;
        }
    }
    __syncthreads();
    // t-partials: thread (i, kh) accumulates 12 capsules over 64 rows
    {
        const int i = t & 255, kh = t >> 8;
        float a[12];
        #pragma unroll
        for (int j = 0; j < 12; ++j) a[j] = 0.f;
        for (int n = 0; n < CH; ++n) {
            const float uv = u_lds[n * 257 + i];
            const float4* cr = (const float4*)(c_lds + n * 28 + kh * 12);
            const float4 c0 = cr[0], c1 = cr[1], c2 = cr[2];
            a[0] += uv * c0.x; a[1] += uv * c0.y; a[2]  += uv * c0.z; a[3]  += uv * c0.w;
            a[4] += uv * c1.x; a[5] += uv * c1.y; a[6]  += uv * c1.z; a[7]  += uv * c1.w;
            a[8] += uv * c2.x; a[9] += uv * c2.y; a[10] += uv * c2.z; a[11] += uv * c2.w;
        }
        float* tp = tpart + (size_t)(beta * K_ + kh * 12) * DIN + i;
        #pragma unroll
        for (int j = 0; j < 12; ++j) cs(tp + (size_t)j * DIN, a[j]);
    }
    const int rank = arrive(cnt + b * 16, t, &rank_sh);
    if (rank < 0) return;
    if (LAST) sv_tail<2>(b, rank, t, W, nullptr, tpart, nullptr, outv, t_lds, s_lds, v_lds);
    else      sv_tail<1>(b, rank, t, W, nullptr, tpart, w2out, nullptr, t_lds, s_lds, v_lds);
}

extern "C" void kernel_launch(void* const* d_in, const int* in_sizes, int n_in,
                              void* d_out, int out_size, void* d_ws, size_t ws_size,
                              hipStream_t stream) {
    const float* u = (const float*)d_in[0];   // [16,1024,256]
    const float* W = (const float*)d_in[1];   // [256,3072]
    float* out = (float*)d_out;               // [16,24,128]

    char* ws = (char*)d_ws;
    float* tpart  = (float*)ws;                    // 6,291,456 B
    float* tupart = (float*)(ws + 6291456);        //   262,144 B
    float* w2a    = (float*)(ws + 6553600);        //   393,216 B
    float* w2b    = (float*)(ws + 6946816);        //   393,216 B
    unsigned* cnt = (unsigned*)(ws + 7340032);     //     3,072 B (3 x 16 x 64B)

    hipMemsetAsync(cnt, 0, 3072, stream);  // reset per call (graph-captured)

    k0<<<dim3(256), dim3(512), 0, stream>>>(u, W, tupart, w2a, cnt);
    kfused<0><<<dim3(256), dim3(512), 0, stream>>>(u, W, w2a, tpart, w2b, nullptr, cnt + 256);
    kfused<1><<<dim3(256), dim3(512), 0, stream>>>(u, W, w2b, tpart, nullptr, out, cnt + 512);
}

// Round 11
// 93.192 us; speedup vs baseline: 1.8476x; 1.8476x over previous
//
#include <hip/hip_runtime.h>

#define DIN 256
#define K_ 24
#define D_ 128
#define KD_ 3072
#define CH 64        /* rows per block chunk */
#define NS 16        /* chunks per batch */
#define EPS_ 1e-7f

// sc1 (agent-scope) accessors: single L2-bypassing load/store, no cache ops.
__device__ __forceinline__ float cl(const float* p) {
    return __hip_atomic_load(p, __ATOMIC_RELAXED, __HIP_MEMORY_SCOPE_AGENT);
}
__device__ __forceinline__ void cs(float* p, float v) {
    __hip_atomic_store(p, v, __ATOMIC_RELAXED, __HIP_MEMORY_SCOPE_AGENT);
}
__device__ __forceinline__ unsigned clu(const unsigned* p) {
    return __hip_atomic_load(p, __ATOMIC_RELAXED, __HIP_MEMORY_SCOPE_AGENT);
}
__device__ __forceinline__ void fadd(unsigned* p) {
    __hip_atomic_fetch_add(p, 1u, __ATOMIC_RELAXED, __HIP_MEMORY_SCOPE_AGENT);
}

// Per-batch rendezvous of all 16 sibling blocks. Ordering (proven r9/r10):
// each wave's sc1 stores are vmcnt(0)-drained by the __syncthreads before the
// leader's relaxed fadd, so cnt==16 => all siblings' data is MALL-visible.
__device__ __forceinline__ void arrive_wait(unsigned* cnt_b, int t) {
    __syncthreads();
    if (t == 0) {
        fadd(cnt_b);
        while (clu(cnt_b) < 16u) __builtin_amdgcn_s_sleep(1);
    }
    __syncthreads();
    asm volatile("" ::: "memory");
}

// ---- sv unit: one capsule k of batch b; t_lds[256] pre-filled. 512 threads.
// MODE 1: compute v, write w2o. MODE 2: write squashed v to outv only.
template<int MODE>
__device__ __forceinline__ void sv_unit(int b, int k, int t,
                                        const float* __restrict__ W,
                                        float* __restrict__ w2o,
                                        float* __restrict__ outv,
                                        const float* t_lds, float* sred,
                                        float* red2, float* v_lds) {
    // s-pass: d = t&127, i-quarter q = t>>7
    {
        const int d = t & 127, q = t >> 7;
        const float* Wp = W + (size_t)(q * 64) * KD_ + (size_t)k * D_ + d;
        const float* tp = t_lds + q * 64;
        float sd = 0.f;
        #pragma unroll 8
        for (int i = 0; i < 64; ++i) sd += tp[i] * Wp[(size_t)i * KD_];
        sred[(t >> 7) * 128 + d] = sd;
    }
    __syncthreads();
    float sd = 0.f;
    if (t < 128) {
        sd = (sred[t] + sred[128 + t]) + (sred[256 + t] + sred[384 + t]);
        float sq = sd * sd;
        #pragma unroll
        for (int m = 1; m < 64; m <<= 1) sq += __shfl_xor(sq, m);
        if ((t & 63) == 0) red2[t >> 6] = sq;
    }
    __syncthreads();
    const float inv = rsqrtf(red2[0] + red2[1] + EPS_);
    if (t < 128) {
        const float vd = sd * inv;
        if (MODE == 2) outv[(size_t)(b * K_ + k) * D_ + t] = vd;
        else v_lds[t] = vd;
    }
    if (MODE != 2) {
        __syncthreads();
        // w2[i] = sum_d v[d]*W[i,k*128+d]; i = t>>1, d-half dh = t&1
        const int i = t >> 1, dh = t & 1;
        const float4* Wq = (const float4*)(W + (size_t)i * KD_ + (size_t)k * D_ + dh * 64);
        const float4* vq = (const float4*)(v_lds + dh * 64);
        float a = 0.f;
        #pragma unroll
        for (int m2 = 0; m2 < 16; ++m2) {
            const float4 wv = Wq[m2], vv = vq[m2];
            a += wv.x * vv.x + wv.y * vv.y + wv.z * vv.z + wv.w * vv.w;
        }
        a += __shfl_xor(a, 1);
        if (dh == 0) cs(w2o + (size_t)(b * K_ + k) * DIN + i, a);
    }
}

// ---- K0: colsum -> tupart; rendezvous; all 16 blocks sv their capsules -> w2a
__global__ __launch_bounds__(512) void k0(const float* __restrict__ u,
                                          const float* __restrict__ W,
                                          float* __restrict__ tupart,
                                          float* __restrict__ w2a,
                                          unsigned* __restrict__ cnt) {
    const int beta = blockIdx.x, b = beta >> 4, sblk = beta & 15, t = threadIdx.x;
    __shared__ float red[8 * DIN];                 // 8 KB
    __shared__ float t_lds[DIN], sred[512], red2[2];
    __shared__ __align__(16) float v_lds[128];
    // colsum of this chunk
    {
        const float4* ug = (const float4*)(u + (size_t)beta * CH * DIN);
        const int g = t & 63, h = t >> 6;
        float ax = 0.f, ay = 0.f, az = 0.f, aw = 0.f;
        #pragma unroll
        for (int r = 0; r < 8; ++r) {
            const float4 v = ug[(size_t)(h * 8 + r) * 64 + g];
            ax += v.x; ay += v.y; az += v.z; aw += v.w;
        }
        float* dst = red + h * DIN + g * 4;
        dst[0] = ax; dst[1] = ay; dst[2] = az; dst[3] = aw;
    }
    __syncthreads();
    if (t < DIN) {
        float a = 0.f;
        #pragma unroll
        for (int h2 = 0; h2 < 8; ++h2) a += red[h2 * DIN + t];
        cs(tupart + (size_t)beta * DIN + t, a);
    }
    arrive_wait(cnt + b * 16, t);
    // uniform t (same for all capsules): reduce tupart once, scale 1/24
    if (t < DIN) {
        float a = 0.f;
        #pragma unroll
        for (int s2 = 0; s2 < NS; ++s2)
            a += cl(tupart + (size_t)(b * NS + s2) * DIN + t);
        t_lds[t] = a * (1.f / 24.f);
    }
    __syncthreads();
    sv_unit<1>(b, sblk, t, W, w2a, nullptr, t_lds, sred, red2, v_lds);
    if (sblk < 8) {
        __syncthreads();
        sv_unit<1>(b, 16 + sblk, t, W, w2a, nullptr, t_lds, sred, red2, v_lds);
    }
}

// ---- K1/K2: fused (logits+softmax+t-partials); rendezvous; distributed sv
template<int LAST>
__global__ __launch_bounds__(512) void kfused(const float* __restrict__ u,
                                              const float* __restrict__ W,
                                              const float* __restrict__ w2in,
                                              float* __restrict__ tpart,
                                              float* __restrict__ w2out,
                                              float* __restrict__ outv,
                                              unsigned* __restrict__ cnt) {
    const int beta = blockIdx.x, b = beta >> 4, sblk = beta & 15, t = threadIdx.x;
    __shared__ float u_lds[CH * 257];                 // 65,792 B
    __shared__ __align__(16) float w2_lds[K_ * DIN];  // 24,576 B
    __shared__ __align__(16) float c_lds[CH * 28];    //  7,168 B
    __shared__ float t_lds[DIN], sred[512], red2[2];
    __shared__ __align__(16) float v_lds[128];
    // stage u chunk + w2in[b]
    {
        const float4* ug = (const float4*)(u + (size_t)beta * CH * DIN);
        #pragma unroll
        for (int r = 0; r < 8; ++r) {
            const int idx = t + r * 512, n = idx >> 6, q = idx & 63;
            const float4 v = ug[(size_t)n * 64 + q];
            float* dst = u_lds + n * 257 + q * 4;
            dst[0] = v.x; dst[1] = v.y; dst[2] = v.z; dst[3] = v.w;
        }
        const float* w2g = w2in + (size_t)b * K_ * DIN;
        #pragma unroll
        for (int r = 0; r < 12; ++r)
            w2_lds[r * 512 + t] = cl(w2g + r * 512 + t);
    }
    __syncthreads();
    // logits + softmax (8-lane groups per n; lane p==0 writes 24 c's, STATIC idx)
    {
        const int n = t >> 3, p = t & 7;
        float acc[K_];
        #pragma unroll
        for (int k = 0; k < K_; ++k) acc[k] = 0.f;
        #pragma unroll
        for (int g = 0; g < 8; ++g) {
            const int i0 = p * 4 + g * 32;
            const float ua0 = u_lds[n * 257 + i0],     ua1 = u_lds[n * 257 + i0 + 1];
            const float ua2 = u_lds[n * 257 + i0 + 2], ua3 = u_lds[n * 257 + i0 + 3];
            #pragma unroll
            for (int k = 0; k < K_; ++k) {
                const float4 wq = *(const float4*)(w2_lds + k * DIN + i0);
                acc[k] += ua0 * wq.x + ua1 * wq.y + ua2 * wq.z + ua3 * wq.w;
            }
        }
        #pragma unroll
        for (int m = 1; m < 8; m <<= 1)
            #pragma unroll
            for (int k = 0; k < K_; ++k) acc[k] += __shfl_xor(acc[k], m);
        float mx = acc[0];
        #pragma unroll
        for (int k = 1; k < K_; ++k) mx = fmaxf(mx, acc[k]);
        float sm = 0.f;
        #pragma unroll
        for (int k = 0; k < K_; ++k) { acc[k] = __expf(acc[k] - mx); sm += acc[k]; }
        const float cinv = 1.f / sm;
        if (p == 0) {
            #pragma unroll
            for (int k = 0; k < K_; ++k) c_lds[n * 28 + k] = acc[k] * cinv;
        }
    }
    __syncthreads();
    // t-partials: thread (i = t&255, kh = t>>8) accumulates 12 capsules
    {
        const int i = t & 255, kh = t >> 8;
        float a[12];
        #pragma unroll
        for (int j = 0; j < 12; ++j) a[j] = 0.f;
        for (int n = 0; n < CH; ++n) {
            const float uv = u_lds[n * 257 + i];
            const float4* cr = (const float4*)(c_lds + n * 28 + kh * 12);
            const float4 c0 = cr[0], c1 = cr[1], c2 = cr[2];
            a[0] += uv * c0.x; a[1] += uv * c0.y; a[2]  += uv * c0.z; a[3]  += uv * c0.w;
            a[4] += uv * c1.x; a[5] += uv * c1.y; a[6]  += uv * c1.z; a[7]  += uv * c1.w;
            a[8] += uv * c2.x; a[9] += uv * c2.y; a[10] += uv * c2.z; a[11] += uv * c2.w;
        }
        float* tp = tpart + (size_t)(beta * K_ + kh * 12) * DIN + i;
        #pragma unroll
        for (int j = 0; j < 12; ++j) cs(tp + (size_t)j * DIN, a[j]);
    }
    arrive_wait(cnt + b * 16, t);
    // distributed sv: capsule sblk, plus 16+sblk for sblk<8
    for (int k = sblk; k < K_; k += 16) {
        __syncthreads();  // protect t_lds/sred reuse across loop iterations
        if (t < DIN) {
            float a = 0.f;
            #pragma unroll
            for (int s2 = 0; s2 < NS; ++s2)
                a += cl(tpart + (size_t)((b * NS + s2) * K_ + k) * DIN + t);
            t_lds[t] = a;
        }
        __syncthreads();
        if (LAST) sv_unit<2>(b, k, t, W, nullptr, outv, t_lds, sred, red2, v_lds);
        else      sv_unit<1>(b, k, t, W, w2out, nullptr, t_lds, sred, red2, v_lds);
    }
}

extern "C" void kernel_launch(void* const* d_in, const int* in_sizes, int n_in,
                              void* d_out, int out_size, void* d_ws, size_t ws_size,
                              hipStream_t stream) {
    const float* u = (const float*)d_in[0];   // [16,1024,256]
    const float* W = (const float*)d_in[1];   // [256,3072]
    float* out = (float*)d_out;               // [16,24,128]

    char* ws = (char*)d_ws;
    float* tpart  = (float*)ws;                    // 6,291,456 B
    float* tupart = (float*)(ws + 6291456);        //   262,144 B
    float* w2a    = (float*)(ws + 6553600);        //   393,216 B
    float* w2b    = (float*)(ws + 6946816);        //   393,216 B
    unsigned* cnt = (unsigned*)(ws + 7340032);     //     3,072 B (3 x 16 x 64B)

    hipMemsetAsync(cnt, 0, 3072, stream);  // reset per call (graph-captured)

    k0<<<dim3(256), dim3(512), 0, stream>>>(u, W, tupart, w2a, cnt);
    kfused<0><<<dim3(256), dim3(512), 0, stream>>>(u, W, w2a, tpart, w2b, nullptr, cnt + 256);
    kfused<1><<<dim3(256), dim3(512), 0, stream>>>(u, W, w2b, tpart, nullptr, out, cnt + 512);
}